// Round 2
// baseline (806.315 us; speedup 1.0000x reference)
//
#include <hip/hip_runtime.h>

#define V     49152
#define NNZ   442368
#define CIN   32
#define COUT  64
#define BATCH 16
#define KCH   4
#define EPS   1e-5f
#define VOUT  (V / 4)
#define VB    16
#define SCP   260   // padded LDS row stride for transposed cheb tile

// ---------------- row_ptr via binary search + zero stats ----------------
__global__ __launch_bounds__(256) void k_rowptr(const int* __restrict__ rows,
                                                int* __restrict__ rp,
                                                float* __restrict__ stats) {
    int r = blockIdx.x * blockDim.x + threadIdx.x;
    if (r <= V) {
        int lo = 0, hi = NNZ;
        while (lo < hi) {
            int m = (lo + hi) >> 1;
            if (rows[m] < r) lo = m + 1; else hi = m;
        }
        rp[r] = lo;
    }
    if (blockIdx.x == 0 && threadIdx.x < 256) stats[threadIdx.x] = 0.f;
}

// ---------------- X1 = L @ X0 (X0 gathered from x [B,V,CIN]) ----------------
__global__ __launch_bounds__(256) void k_spmm1(const float* __restrict__ x,
                                               const int* __restrict__ cols,
                                               const float* __restrict__ vals,
                                               const int* __restrict__ rp,
                                               float* __restrict__ X12) {
    int v = blockIdx.x, t = threadIdx.x;
    int s = rp[v], e = rp[v + 1];
    int f1 = t + 256;
    int i0 = t & 31, b0 = t >> 5, i1 = f1 & 31, b1 = f1 >> 5;
    float a0 = 0.f, a1 = 0.f;
    for (int n = s; n < e; ++n) {
        int c = cols[n];
        float w = vals[n];
        a0 = fmaf(w, x[(b0 * V + c) * CIN + i0], a0);
        a1 = fmaf(w, x[(b1 * V + c) * CIN + i1], a1);
    }
    X12[(size_t)v * 1024 + t]  = a0;
    X12[(size_t)v * 1024 + f1] = a1;
}

// ---------------- X2 = 2 L @ X1 - X0 ----------------
__global__ __launch_bounds__(256) void k_spmm2(const float* __restrict__ x,
                                               const int* __restrict__ cols,
                                               const float* __restrict__ vals,
                                               const int* __restrict__ rp,
                                               float* __restrict__ X12) {
    int v = blockIdx.x, t = threadIdx.x;
    int s = rp[v], e = rp[v + 1];
    int f1 = t + 256;
    int i0 = t & 31, b0 = t >> 5, i1 = f1 & 31, b1 = f1 >> 5;
    float a0 = 0.f, a1 = 0.f;
    for (int n = s; n < e; ++n) {
        int c = cols[n];
        float w = vals[n];
        a0 = fmaf(w, X12[(size_t)c * 1024 + t], a0);
        a1 = fmaf(w, X12[(size_t)c * 1024 + f1], a1);
    }
    X12[(size_t)v * 1024 + 512 + t]  = 2.f * a0 - x[(b0 * V + v) * CIN + i0];
    X12[(size_t)v * 1024 + 512 + f1] = 2.f * a1 - x[(b1 * V + v) * CIN + i1];
}

// ---------------- X3 = 2 L @ X2 - X1 ----------------
__global__ __launch_bounds__(256) void k_spmm3(const int* __restrict__ cols,
                                               const float* __restrict__ vals,
                                               const int* __restrict__ rp,
                                               const float* __restrict__ X12,
                                               float* __restrict__ X3) {
    int v = blockIdx.x, t = threadIdx.x;
    int s = rp[v], e = rp[v + 1];
    int f1 = t + 256;
    float a0 = 0.f, a1 = 0.f;
    for (int n = s; n < e; ++n) {
        int c = cols[n];
        float w = vals[n];
        a0 = fmaf(w, X12[(size_t)c * 1024 + 512 + t], a0);
        a1 = fmaf(w, X12[(size_t)c * 1024 + 512 + f1], a1);
    }
    X3[(size_t)v * 512 + t]  = 2.f * a0 - X12[(size_t)v * 1024 + t];
    X3[(size_t)v * 512 + f1] = 2.f * a1 - X12[(size_t)v * 1024 + f1];
}

// ---------------- einsum + BN-stats; y overwrites X12 (safe per-block aliasing) ----------------
__global__ __launch_bounds__(256) void k_einsum(const float* __restrict__ x,
                                                const float* __restrict__ X3,
                                                const float* __restrict__ W,
                                                float* __restrict__ X12,
                                                float* __restrict__ stats) {
    __shared__ float sW[CIN * COUT];   // 8 KB, W_k as [i][o]
    __shared__ float sC[CIN * SCP];    // ~33.3 KB, cheb_k transposed: sC[i*SCP + r]
    __shared__ float lsum[COUT], lsq[COUT];

    int t = threadIdx.x;
    int v0 = blockIdx.x * VB;
    int to = t & 7, tr = t >> 3;
    int r0 = tr * 8, o0 = to * 8;

    float acc[8][8];
#pragma unroll
    for (int j = 0; j < 8; ++j)
#pragma unroll
        for (int l = 0; l < 8; ++l) acc[j][l] = 0.f;
    if (t < COUT) { lsum[t] = 0.f; lsq[t] = 0.f; }

    for (int k = 0; k < KCH; ++k) {
        __syncthreads();
        // stage W_k (512 float4)
        for (int j = t; j < 512; j += 256)
            *(float4*)&sW[j * 4] = *(const float4*)&W[k * 2048 + j * 4];
        // stage cheb_k tile, transposed into sC[i][r]
        for (int j = t; j < 2048; j += 256) {
            int r = j >> 3, i4 = j & 7;
            int vv = r >> 4, b = r & 15;
            int v = v0 + vv;
            float4 val;
            if (k == 0)      val = *(const float4*)&x[(size_t)(b * V + v) * CIN + i4 * 4];
            else if (k == 1) val = *(const float4*)&X12[(size_t)v * 1024 + b * CIN + i4 * 4];
            else if (k == 2) val = *(const float4*)&X12[(size_t)v * 1024 + 512 + b * CIN + i4 * 4];
            else             val = *(const float4*)&X3[(size_t)v * 512 + b * CIN + i4 * 4];
            int ib = i4 * 4;
            sC[(ib + 0) * SCP + r] = val.x;
            sC[(ib + 1) * SCP + r] = val.y;
            sC[(ib + 2) * SCP + r] = val.z;
            sC[(ib + 3) * SCP + r] = val.w;
        }
        __syncthreads();
#pragma unroll
        for (int i = 0; i < CIN; ++i) {
            float4 ca = *(const float4*)&sC[i * SCP + r0];
            float4 cb = *(const float4*)&sC[i * SCP + r0 + 4];
            float4 wa = *(const float4*)&sW[i * COUT + o0];
            float4 wb = *(const float4*)&sW[i * COUT + o0 + 4];
            float c[8] = {ca.x, ca.y, ca.z, ca.w, cb.x, cb.y, cb.z, cb.w};
            float w[8] = {wa.x, wa.y, wa.z, wa.w, wb.x, wb.y, wb.z, wb.w};
#pragma unroll
            for (int j = 0; j < 8; ++j)
#pragma unroll
                for (int l = 0; l < 8; ++l)
                    acc[j][l] = fmaf(c[j], w[l], acc[j][l]);
        }
    }
    __syncthreads();

    // write y rows (alias of X12: only this block's vertices, all reads already done)
#pragma unroll
    for (int j = 0; j < 8; ++j) {
        int r = r0 + j;
        int vv = r >> 4, b = r & 15;
        float* yp = &X12[(size_t)(v0 + vv) * 1024 + b * 64 + o0];
        float4 ya = {acc[j][0], acc[j][1], acc[j][2], acc[j][3]};
        float4 yb = {acc[j][4], acc[j][5], acc[j][6], acc[j][7]};
        *(float4*)yp       = ya;
        *(float4*)(yp + 4) = yb;
    }

    // BN partial sums
#pragma unroll
    for (int l = 0; l < 8; ++l) {
        float s = 0.f, q = 0.f;
#pragma unroll
        for (int j = 0; j < 8; ++j) { float a = acc[j][l]; s += a; q = fmaf(a, a, q); }
        atomicAdd(&lsum[o0 + l], s);
        atomicAdd(&lsq[o0 + l], q);
    }
    __syncthreads();
    if (t < COUT) {
        atomicAdd(&stats[t], lsum[t]);
        atomicAdd(&stats[COUT + t], lsq[t]);
    }
}

// ---------------- finalize BN scale/shift ----------------
__global__ void k_bnfin(const float* __restrict__ gamma, const float* __restrict__ beta,
                        float* __restrict__ stats) {
    int o = threadIdx.x;
    if (o < COUT) {
        float n = (float)(BATCH * V);
        float mean = stats[o] / n;
        float var = stats[COUT + o] / n - mean * mean;
        float sc = gamma[o] * rsqrtf(var + EPS);
        stats[128 + o] = sc;
        stats[192 + o] = beta[o] - mean * sc;
    }
}

// ---------------- BN apply + ReLU + pool(4) ----------------
__global__ __launch_bounds__(256) void k_pool(const float* __restrict__ y,
                                              const float* __restrict__ stats,
                                              float* __restrict__ out) {
    int id = blockIdx.x * blockDim.x + threadIdx.x;  // 3,145,728 float4 outputs
    int o4 = id & 15;
    int b  = (id >> 4) & 15;
    int vp = id >> 8;
    float4 sc = *(const float4*)&stats[128 + o4 * 4];
    float4 sh = *(const float4*)&stats[192 + o4 * 4];
    float ax = 0.f, ay = 0.f, az = 0.f, aw = 0.f;
#pragma unroll
    for (int j = 0; j < 4; ++j) {
        float4 t = *(const float4*)&y[(size_t)((vp * 4 + j) * 16 + b) * 64 + o4 * 4];
        ax += fmaxf(fmaf(t.x, sc.x, sh.x), 0.f);
        ay += fmaxf(fmaf(t.y, sc.y, sh.y), 0.f);
        az += fmaxf(fmaf(t.z, sc.z, sh.z), 0.f);
        aw += fmaxf(fmaf(t.w, sc.w, sh.w), 0.f);
    }
    float4 res = {ax * 0.25f, ay * 0.25f, az * 0.25f, aw * 0.25f};
    *(float4*)&out[(size_t)((b * VOUT + vp) * 16 + o4) * 4] = res;
}

extern "C" void kernel_launch(void* const* d_in, const int* in_sizes, int n_in,
                              void* d_out, int out_size, void* d_ws, size_t ws_size,
                              hipStream_t stream) {
    const float* x     = (const float*)d_in[0];
    const float* vals  = (const float*)d_in[1];
    const float* W     = (const float*)d_in[2];
    const float* gamma = (const float*)d_in[3];
    const float* beta  = (const float*)d_in[4];
    const int*   rows  = (const int*)d_in[5];
    const int*   cols  = (const int*)d_in[6];
    float* out = (float*)d_out;

    char* ws = (char*)d_ws;
    float* X12   = (float*)ws;                                   // 201,326,592 B (X1|X2 per vertex, later y)
    float* X3    = (float*)(ws + 201326592UL);                   // 100,663,296 B
    int*   rp    = (int*)(ws + 201326592UL + 100663296UL);       // 196,612 B
    float* stats = (float*)(ws + 201326592UL + 100663296UL + 197120UL); // 1 KB

    k_rowptr<<<193, 256, 0, stream>>>(rows, rp, stats);
    k_spmm1<<<V, 256, 0, stream>>>(x, cols, vals, rp, X12);
    k_spmm2<<<V, 256, 0, stream>>>(x, cols, vals, rp, X12);
    k_spmm3<<<V, 256, 0, stream>>>(cols, vals, rp, X12, X3);
    k_einsum<<<V / VB, 256, 0, stream>>>(x, X3, W, X12, stats);
    k_bnfin<<<1, 64, 0, stream>>>(gamma, beta, stats);
    k_pool<<<12288, 256, 0, stream>>>(X12, stats, out);
}